// Round 2
// 113.249 us; speedup vs baseline: 1.0557x; 1.0557x over previous
//
#include <hip/hip_runtime.h>
#include <math.h>

#define B_ 16
#define L_ 128
#define D_ 768
#define H1_ 770
#define OUT_ 40
#define NPAIRS 3405     // sum over i of min(30, 128-i)
#define NLOG 1540       // logical cols of Y: U(770) || V(770)
#define YSB 1552        // bf16 Y row stride in shorts (16B-aligned rows)
#define VOFFB 776       // V part at +776 shorts (1552 B, 16B-aligned)
#define KPAD 800        // 25 x 32 MFMA k-steps (k >= 770 zero-padded in B/Cv)
#define W1TROWS 1600    // W1T rows padded (zeros in [1540,1600)) for safe staging
#define NKS 25
#define NTILES 252      // 4x4 (i,j) tiles covering the band
#define BSWZ_N (26 * 3 * 512)   // 25 real k-steps + 1 zero step (legacy pad)

// virtual block ranges
#define NB_X 1536      // X convert: 2048*192 vec4-units / 256
#define NB_W 166       // Bswz (26*3*512) + Cv (3*800), ceil(42336/256)
#define NB_T 1200      // W1T transpose: 50 n-tiles x 24 k-tiles
#define NB_A (NB_X + NB_W + NB_T)
#define NB_B 800       // gemm tiles 25 cols x 32 row-panels
#define NB_C (63 * 8)  // pair: 63 tile-groups x 8 batch-groups, 8 waves/block

typedef __attribute__((ext_vector_type(8))) short bf16x8;
typedef __attribute__((ext_vector_type(8))) unsigned short u16x8;
typedef __attribute__((ext_vector_type(4))) float f32x4;
typedef __attribute__((ext_vector_type(2))) float f32x2;
typedef __attribute__((ext_vector_type(4))) unsigned int u32x4;

__device__ inline unsigned short f2bf(float f) {
  unsigned int u = __builtin_bit_cast(unsigned int, f);
  u += 0x7fffu + ((u >> 16) & 1u);          // round-to-nearest-even
  return (unsigned short)(u >> 16);
}
__device__ inline float bf2f(unsigned short x) {
  return __builtin_bit_cast(float, (unsigned int)x << 16);
}
// exact bf16-pair -> f32x2 unpack (lo = d<<16, hi = d & 0xffff0000)
__device__ inline f32x2 unpk_bf(unsigned int d) {
  f32x2 r;
  r[0] = __builtin_bit_cast(float, d << 16);
  r[1] = __builtin_bit_cast(float, d & 0xffff0000u);
  return r;
}

#if __has_builtin(__builtin_amdgcn_cvt_pk_bf16_f32)
typedef __attribute__((ext_vector_type(2))) __bf16 bf16x2_t;
__device__ inline unsigned int pack_bf16(float lo, float hi) {
  bf16x2_t r = __builtin_amdgcn_cvt_pk_bf16_f32(lo, hi);
  return __builtin_bit_cast(unsigned int, r);
}
#else
__device__ inline unsigned int pack_bf16(float lo, float hi) {
  return (unsigned int)f2bf(lo) | ((unsigned int)f2bf(hi) << 16);
}
#endif

// async global->LDS, 16B per lane; LDS dest = wave-uniform base + lane*16,
// GLOBAL source is PER-LANE (must include the lane offset explicitly!)
typedef const __attribute__((address_space(1))) void* gas_t;
typedef __attribute__((address_space(3))) void* las_t;
__device__ inline void gl2lds16(const void* g, void* l) {
  __builtin_amdgcn_global_load_lds((gas_t)g, (las_t)l, 16, 0, 0);
}

// tile decode: T -> (ti, d); tile = i in [4ti,4ti+4) x j in [4(ti+d),+4)
__device__ inline void tile_decode(int T, int& ti, int& d) {
  if (T < 216) { ti = T / 9; d = T - ti * 9; }
  else {
    int m = T - 216; int r = 24, w = 8;
    while (m >= w) { m -= w; --w; ++r; }
    ti = r; d = m;
  }
}
// row-major rank of an in-band pair (i,j)
__device__ inline int pair_rank(int i, int j) {
  return (i < 99) ? i * 30 + (j - i)
                  : NPAIRS - (128 - i) * (129 - i) / 2 + (j - i);
}

// ---------------------------------------------------------------------------
// Kernel A: prep (X bf16 convert | Bswz/Cv | W1T transpose)
// ---------------------------------------------------------------------------
__global__ __launch_bounds__(256) void prep_k(
    const float* __restrict__ hidden, const float* __restrict__ W1,
    const float* __restrict__ b1, const float* __restrict__ W2,
    unsigned short* __restrict__ Xb, unsigned short* __restrict__ W1T,
    unsigned short* __restrict__ Bswz, float* __restrict__ Cv)
{
  __shared__ float t[32][33];
  const int u = blockIdx.x;
  const int tid = threadIdx.x;

  if (u < NB_X) {                        // ---- X convert ----
    int idx = u * 256 + tid;
    int m = idx / 192;
    int c = idx - m * 192;
    float4 f = *(const float4*)(hidden + (size_t)(m + (m >> 7) + 1) * D_ + c * 4);
    ushort4 o;
    o.x = f2bf(f.x); o.y = f2bf(f.y); o.z = f2bf(f.z); o.w = f2bf(f.w);
    *(ushort4*)(Xb + (size_t)m * D_ + c * 4) = o;
  } else if (u < NB_X + NB_W) {          // ---- Bswz + Cv ----
    int idx = (u - NB_X) * 256 + tid;
    if (idx < BSWZ_N) {                  // ks=25 block is all zeros (pad)
      int ks = idx / 1536;
      int rem = idx - ks * 1536;
      int f = rem / 512;
      int l = (rem - f * 512) >> 3;
      int e = rem & 7;
      int n = f * 16 + (l & 15);
      int k = ks * 32 + (l >> 4) * 8 + e;
      float v = (n < OUT_ && k < H1_) ? W2[k * OUT_ + n] : 0.f;
      Bswz[idx] = f2bf(v);
    } else if (idx < BSWZ_N + 3 * KPAD) {
      int c = idx - BSWZ_N;
      int tt = c / KPAD, k = c - tt * KPAD;
      const float* w1c = W1 + 1536 * H1_;
      Cv[c] = (k < H1_) ? (b1[k] + (float)tt * w1c[k]) : 0.f;
    }
  } else {                               // ---- W1T transpose ----
    int bx = u - NB_X - NB_W;
    const int tx = tid & 31, ty = tid >> 5;
    const int n0 = (bx % 50) * 32, k0 = (bx / 50) * 32;
    #pragma unroll
    for (int r = 0; r < 4; ++r) {
      int k = k0 + ty + r * 8, n = n0 + tx;
      float v = 0.f;
      if (n < H1_)       v = W1[k * H1_ + n];
      else if (n < NLOG) v = W1[(D_ + k) * H1_ + (n - H1_)];
      t[ty + r * 8][tx] = v;
    }
    __syncthreads();
    #pragma unroll
    for (int r = 0; r < 4; ++r) {
      int n = n0 + ty + r * 8, k = k0 + tx;
      W1T[(size_t)n * D_ + k] = f2bf(t[tx][ty + r * 8]);   // n < 1600 always
    }
  }
}

// ---------------------------------------------------------------------------
// Kernel B: Yb = Xb @ W1T^T (bf16), 64x64 tile, BK=64, global_load_lds,
// XOR chunk swizzle (conflict-free), XCD panel swizzle: block u -> XCD u&7
// works row-panels [4*(u&7), +4) so each XCD's L2 holds A 0.4MB + B 2.4MB.
// ---------------------------------------------------------------------------
__global__ __launch_bounds__(256) void gemm_k(
    const unsigned short* __restrict__ Xb, const unsigned short* __restrict__ W1T,
    unsigned short* __restrict__ Yb)
{
  __shared__ unsigned short As[64][64];
  __shared__ unsigned short Bs[64][64];
  const int tid = threadIdx.x;
  const int lane = tid & 63, w = tid >> 6;
  const int lm = lane & 15, q = lane >> 4;
  const int xcd = blockIdx.x & 7;
  const int t = blockIdx.x >> 3;                 // 0..99
  const int col0 = (t % 25) * 64;
  const int row0 = (xcd * 4 + t / 25) * 64;      // all 32 panels covered
  const int m0 = (w >> 1) * 32, n0 = (w & 1) * 32;

  // staging: wave w owns rows [w*16,+16); lane -> row +l/8, SWIZZLED chunk
  const int srow = w * 16 + (lane >> 3);
  const int schunk = (((lane & 7) ^ ((lane >> 3) & 7))) * 8;
  const unsigned short* ga = Xb  + (size_t)(row0 + srow) * D_ + schunk;
  const unsigned short* gb = W1T + (size_t)(col0 + srow) * D_ + schunk;

  const int xs = lm & 7;                 // read-side xor key (row & 7)

  f32x4 acc[2][2] = {};

  for (int k0 = 0; k0 < D_; k0 += 64) {
    gl2lds16(ga + k0,          &As[w * 16][0]);
    gl2lds16(ga + k0 + 8 * D_, &As[w * 16 + 8][0]);
    gl2lds16(gb + k0,          &Bs[w * 16][0]);
    gl2lds16(gb + k0 + 8 * D_, &Bs[w * 16 + 8][0]);
    __syncthreads();
    #pragma unroll
    for (int ks = 0; ks < 2; ++ks) {
      const int cc = ((ks * 4 + q) ^ xs) * 8;
      bf16x8 a0 = *(const bf16x8*)&As[m0 + lm]     [cc];
      bf16x8 a1 = *(const bf16x8*)&As[m0 + 16 + lm][cc];
      bf16x8 b0 = *(const bf16x8*)&Bs[n0 + lm]     [cc];
      bf16x8 b1 = *(const bf16x8*)&Bs[n0 + 16 + lm][cc];
      acc[0][0] = __builtin_amdgcn_mfma_f32_16x16x32_bf16(a0, b0, acc[0][0], 0, 0, 0);
      acc[0][1] = __builtin_amdgcn_mfma_f32_16x16x32_bf16(a0, b1, acc[0][1], 0, 0, 0);
      acc[1][0] = __builtin_amdgcn_mfma_f32_16x16x32_bf16(a1, b0, acc[1][0], 0, 0, 0);
      acc[1][1] = __builtin_amdgcn_mfma_f32_16x16x32_bf16(a1, b1, acc[1][1], 0, 0, 0);
    }
    __syncthreads();
  }

  // epilogue: C/D layout col=lane&15, row=q*4+r; store bf16
  #pragma unroll
  for (int ti = 0; ti < 2; ++ti) {
    #pragma unroll
    for (int tj = 0; tj < 2; ++tj) {
      int col = col0 + n0 + tj * 16 + lm;
      if (col >= NLOG) continue;
      int pc = (col < H1_) ? col : col + (VOFFB - H1_);
      #pragma unroll
      for (int r = 0; r < 4; ++r) {
        int row = row0 + m0 + ti * 16 + q * 4 + r;
        Yb[(size_t)row * YSB + pc] = f2bf(acc[ti][tj][r]);
      }
    }
  }
}

// ---------------------------------------------------------------------------
// Kernel C: pair — 8 waves per block (512 thr), grid 63 tile-groups x 8
// batch-groups. Wave w handles tile T = 4*(u>>3) + (w&3) for batch
// bb = 2*(u&7) + (w>>2): block u lands on XCD u%8, so each XCD's L2 holds
// only 2 batches of Y (0.79MB). The 76.8KB Bswz B-matrix (identical for all
// waves) is staged ONCE per block into LDS (one barrier), then the main loop
// runs barrier-free: U/V keep the depth-2 register prefetch from global, and
// the 3 B-fragments/iter come from LDS (conflict-free contiguous
// ds_read_b128) instead of costing 48 L1 lines/iter/wave on the vector-mem
// pipe. h-compute uses exact packed f32x2 math (v_pk_add/max_f32).
// NOTE: global_load_lds source addr is PER-LANE -> each lane supplies
// Bswz + c*512 + lane*8 (lane*16 bytes); LDS dest is uniform + lane*16.
// ---------------------------------------------------------------------------
__global__ __launch_bounds__(512) void pair_k(
    const unsigned short* __restrict__ Yb, const int* __restrict__ spans,
    const unsigned short* __restrict__ Bswz, const float* __restrict__ Cv,
    const float* __restrict__ b2, float* __restrict__ out)
{
  __shared__ unsigned short Blds[NKS * 3 * 512];   // 76800 B
  const int tid = threadIdx.x;           // 0..511
  const int w = tid >> 6;                // wave 0..7
  const int lane = tid & 63;
  const int u = blockIdx.x;
  const int bb = ((u & 7) << 1) | (w >> 2);        // 0..15
  const int T = (u >> 3) * 4 + (w & 3);            // 0..251
  const int lm = lane & 15, q = lane >> 4;

  // ---- stage full B into LDS (per-lane global src, uniform LDS base) ----
  for (int c = w; c < NKS * 3; c += 8)
    gl2lds16(Bswz + (size_t)c * 512 + lane * 8, &Blds[c * 512]);

  int ti, d;
  tile_decode(T, ti, d);
  const int i0 = ti * 4, j0 = (ti + d) * 4;

  const int ai = i0 + (lm & 3);
  const int aj = j0 + (lm >> 2);
  const int s = spans[2 * bb], e = spans[2 * bb + 1];
  const int ind = (ai == s && aj == e) ? 2 : ((ai >= s && aj <= e) ? 1 : 0);

  const unsigned short* uptr = Yb + (size_t)(bb * L_ + ai) * YSB + q * 8;
  const unsigned short* vptr = Yb + (size_t)(bb * L_ + aj) * YSB + VOFFB + q * 8;
  const float* cptr = Cv + ind * KPAD + q * 8;
  const unsigned short* bbase = Blds + lane * 8;

  __syncthreads();                       // B staged (drains vmcnt too)

  f32x4 acc0 = {}, acc1 = {}, acc2 = {};

  // pipeline primes: U/V depth 2 (register prefetch from global, unchanged)
  u16x8 uu0 = *(const u16x8*)(uptr);
  u16x8 vv0 = *(const u16x8*)(vptr);
  u16x8 uu1 = *(const u16x8*)(uptr + 32);
  u16x8 vv1 = *(const u16x8*)(vptr + 32);

  #pragma unroll 5
  for (int ks = 0; ks < NKS; ++ks) {
    const int ko = ks * 32;
    u16x8 cu = uu0, cw = vv0;
    uu0 = uu1; vv0 = vv1;
    uu1 = *(const u16x8*)(uptr + ko + 64);   // last overrun lands in spare row
    vv1 = *(const u16x8*)(vptr + ko + 64);
    bf16x8 b0  = *(const bf16x8*)(bbase + (size_t)(ks * 3 + 0) * 512);
    bf16x8 b1v = *(const bf16x8*)(bbase + (size_t)(ks * 3 + 1) * 512);
    bf16x8 b2f = *(const bf16x8*)(bbase + (size_t)(ks * 3 + 2) * 512);
    float4 c0 = *(const float4*)(cptr + ko);
    float4 c1 = *(const float4*)(cptr + ko + 4);
    u32x4 cud = __builtin_bit_cast(u32x4, cu);
    u32x4 cwd = __builtin_bit_cast(u32x4, cw);
    f32x2 cc01; cc01[0] = c0.x; cc01[1] = c0.y;
    f32x2 cc23; cc23[0] = c0.z; cc23[1] = c0.w;
    f32x2 cc45; cc45[0] = c1.x; cc45[1] = c1.y;
    f32x2 cc67; cc67[0] = c1.z; cc67[1] = c1.w;
    f32x2 zz = {};
    f32x2 h01 = __builtin_elementwise_max(unpk_bf(cud[0]) + unpk_bf(cwd[0]) + cc01, zz);
    f32x2 h23 = __builtin_elementwise_max(unpk_bf(cud[1]) + unpk_bf(cwd[1]) + cc23, zz);
    f32x2 h45 = __builtin_elementwise_max(unpk_bf(cud[2]) + unpk_bf(cwd[2]) + cc45, zz);
    f32x2 h67 = __builtin_elementwise_max(unpk_bf(cud[3]) + unpk_bf(cwd[3]) + cc67, zz);
    u32x4 hp;
    hp[0] = pack_bf16(h01[0], h01[1]);
    hp[1] = pack_bf16(h23[0], h23[1]);
    hp[2] = pack_bf16(h45[0], h45[1]);
    hp[3] = pack_bf16(h67[0], h67[1]);
    bf16x8 a = __builtin_bit_cast(bf16x8, hp);
    acc0 = __builtin_amdgcn_mfma_f32_16x16x32_bf16(a, b0, acc0, 0, 0, 0);
    acc1 = __builtin_amdgcn_mfma_f32_16x16x32_bf16(a, b1v, acc1, 0, 0, 0);
    acc2 = __builtin_amdgcn_mfma_f32_16x16x32_bf16(a, b2f, acc2, 0, 0, 0);
  }

  // epilogue: C/D row p=4q+r -> pair (i0+r, j0+q), col lm.
  const float b2v0 = b2[lm];
  const float b2v1 = b2[16 + lm];
  const float b2v2 = (lm < 8) ? b2[32 + lm] : 0.f;

  #pragma unroll
  for (int r = 0; r < 4; ++r) {
    float l0 = acc0[r] + b2v0;
    float l1 = acc1[r] + b2v1;
    float l2 = (lm < 8) ? (acc2[r] + b2v2) : -INFINITY;
    float mx = fmaxf(fmaxf(l0, l1), l2);
    mx = fmaxf(mx, __shfl_xor(mx, 1));
    mx = fmaxf(mx, __shfl_xor(mx, 2));
    mx = fmaxf(mx, __shfl_xor(mx, 4));
    mx = fmaxf(mx, __shfl_xor(mx, 8));
    float sm = expf(l0 - mx) + expf(l1 - mx) + ((lm < 8) ? expf(l2 - mx) : 0.f);
    sm += __shfl_xor(sm, 1);
    sm += __shfl_xor(sm, 2);
    sm += __shfl_xor(sm, 4);
    sm += __shfl_xor(sm, 8);
    float lsd = mx + logf(sm);

    int pi_ = i0 + r, pj_ = j0 + q;
    if (pj_ >= pi_ && (pj_ - pi_) < 30) {
      float* op = out + ((size_t)bb * NPAIRS + pair_rank(pi_, pj_)) * OUT_;
      op[lm]      = l0 - lsd;
      op[16 + lm] = l1 - lsd;
      if (lm < 8) op[32 + lm] = l2 - lsd;
    }
  }
}

// ---------------------------------------------------------------------------
extern "C" void kernel_launch(void* const* d_in, const int* in_sizes, int n_in,
                              void* d_out, int out_size, void* d_ws, size_t ws_size,
                              hipStream_t stream) {
  const float* hidden = (const float*)d_in[0];   // (16,129,768) f32
  const int*   spans  = (const int*)d_in[1];     // (16,2) i32
  const float* W1 = (const float*)d_in[4];       // (1537,770) f32
  const float* b1 = (const float*)d_in[5];       // (770,)
  const float* W2 = (const float*)d_in[6];       // (770,40)
  const float* b2 = (const float*)d_in[7];       // (40,)
  float* out = (float*)d_out;                    // (16,3405,40) f32

  // workspace layout (256B-aligned slabs). Yb has one spare row: pair_k's
  // V prefetch on the last row overruns by <=112 shorts into poisoned-but-
  // finite space (multiplied by Bswz zero pad or never used).
  char* base = (char*)d_ws;
  size_t off = 0;
  auto take = [&](size_t bytes) {
    char* p = base + off;
    off = (off + bytes + 255) & ~(size_t)255;
    return p;
  };
  unsigned short* Yb   = (unsigned short*)take((size_t)2049 * YSB * 2);     // 6.36 MB
  unsigned short* Xb   = (unsigned short*)take((size_t)2048 * D_ * 2);      // 3.15 MB
  unsigned short* W1T  = (unsigned short*)take((size_t)W1TROWS * D_ * 2);   // 2.46 MB
  unsigned short* Bswz = (unsigned short*)take((size_t)BSWZ_N * 2);         // 79.9 KB
  float*          Cv   = (float*)take((size_t)3 * KPAD * 4);                // 9.6 KB

  prep_k<<<dim3(NB_A), 256, 0, stream>>>(hidden, W1, b1, W2, Xb, W1T, Bswz, Cv);
  gemm_k<<<dim3(NB_B), 256, 0, stream>>>(Xb, W1T, Yb);
  pair_k<<<dim3(NB_C), 512, 0, stream>>>(Yb, spans, Bswz, Cv, b2, out);
}